// Round 4
// baseline (66.126 us; speedup 1.0000x reference)
//
#include <hip/hip_runtime.h>
#include <math.h>

#define BATCH 16384
#define N0 57
#define NX 3249          // 57*57
#define GPB 4            // matrices per tile (4*3249 floats = 3249 16B slots, exact)
#define HS 5
#define NCLS 17
#define NTRI 15
#define EPSV 1e-4f
#define NT 16            // tiles per block (grid 256 = 1 block/CU)
#define BUFF 13312       // floats per LDS buffer (3328 16B slots)

// ---------------------------------------------------------------- helpers
template<int CTRL>
__device__ __forceinline__ float dpp_mov0(float x) {
    return __int_as_float(__builtin_amdgcn_update_dpp(
        0, __float_as_int(x), CTRL, 0xF, 0xF, true));
}
// full 64-lane sum, result valid in lane 63, pure VALU (no LDS pipe)
__device__ __forceinline__ float wave_sum64(float x) {
    x += dpp_mov0<0x111>(x);   // row_shr:1
    x += dpp_mov0<0x112>(x);   // row_shr:2
    x += dpp_mov0<0x114>(x);   // row_shr:4
    x += dpp_mov0<0x118>(x);   // row_shr:8
    x += dpp_mov0<0x142>(x);   // row_bcast:15
    x += dpp_mov0<0x143>(x);   // row_bcast:31 -> lane 63 = total
    return x;
}

__device__ __forceinline__ void load_lds16(const float* g, float* l) {
    __builtin_amdgcn_global_load_lds(
        (const __attribute__((address_space(1))) void*)g,
        (__attribute__((address_space(3))) void*)l, 16, 0, 0);
}

// issue one tile's staging: 13 wave-instrs/thread, 52 KB total, linear dest
__device__ __forceinline__ void stage_tile(const float* gbase, float* buf, int tid) {
    #pragma unroll
    for (int r = 0; r < 13; ++r) {
        int slot = r * 256 + tid;
        int cs = slot > 3248 ? 3248 : slot;      // clamp: dup load into pad slot
        load_lds16(gbase + (size_t)cs * 4, &buf[r * 1024 + (tid & 192) * 4]);
    }
}

// ---------------------------------------------------------------- k_setup
// wc[57][8] = W1@W2@W3, rows padded to 8
__global__ __launch_bounds__(128) void k_setup(const float* __restrict__ W1,
                                               const float* __restrict__ W2,
                                               const float* __restrict__ W3,
                                               float* __restrict__ wc_out) {
    __shared__ float w23[100];
    int t = threadIdx.x;
    if (t < 100) {
        int k = t / 5, j = t % 5;
        float acc = 0.f;
        for (int l = 0; l < 10; ++l) acc = fmaf(W2[k * 10 + l], W3[l * 5 + j], acc);
        w23[t] = acc;
    }
    __syncthreads();
    if (t < N0) {
        float r[5];
        #pragma unroll
        for (int j = 0; j < 5; ++j) {
            float acc = 0.f;
            for (int k = 0; k < 20; ++k) acc = fmaf(W1[t * 20 + k], w23[k * 5 + j], acc);
            r[j] = acc;
        }
        float4* o = (float4*)&wc_out[t * 8];
        o[0] = make_float4(r[0], r[1], r[2], r[3]);
        o[1] = make_float4(r[4], 0.f, 0.f, 0.f);
    }
}

// ----------------------------------------------------------------- k_main
// Double-buffered pipeline: counted vmcnt keeps next tile's loads in flight
// across the barriers; compute overlaps the HBM stream.
__global__ __launch_bounds__(256) void k_main(const float* __restrict__ x,
                                              const float* __restrict__ wc,
                                              float* __restrict__ y_out) {
    __shared__ float xs[2 * BUFF];               // 106496 B -> 1 block/CU
    const int tid  = threadIdx.x;
    const int lane = tid & 63;
    const int wave = tid >> 6;

    // per-lane Wc row (left operand of the outer product)
    float wv[HS];
    {
        int a = (lane < N0) ? lane : 0;
        const float4* wp = (const float4*)&wc[a * 8];
        float4 v0 = wp[0];
        float  v4 = wc[a * 8 + 4];
        wv[0] = v0.x; wv[1] = v0.y; wv[2] = v0.z; wv[3] = v0.w; wv[4] = v4;
        if (lane >= N0) { wv[0] = wv[1] = wv[2] = wv[3] = wv[4] = 0.f; }
    }

    const size_t tile0 = (size_t)blockIdx.x * NT;

    // prologue: stage tile 0 into buf0
    stage_tile(x + tile0 * (GPB * NX), xs, tid);

    for (int t = 0; t < NT; ++t) {
        float* cur = xs + (t & 1) * BUFF;
        float* nxt = xs + ((t + 1) & 1) * BUFF;

        if (t + 1 < NT) {
            stage_tile(x + (tile0 + t + 1) * (GPB * NX), nxt, tid);
            // wait tile t only; tile t+1's 13 loads stay in flight
            asm volatile("s_waitcnt vmcnt(13)" ::: "memory");
        } else {
            asm volatile("s_waitcnt vmcnt(0)" ::: "memory");
        }
        __builtin_amdgcn_s_barrier();

        // compute: wave w -> matrix 4t+w; lane a -> column a (x symmetric)
        const float* base = cur + wave * NX;
        float s[HS] = {0.f, 0.f, 0.f, 0.f, 0.f};
        #pragma unroll
        for (int b = 0; b < N0; ++b) {
            float xv = base[b * N0 + lane];      // conflict-free, 2-way alias free
            #pragma unroll
            for (int j = 0; j < HS; ++j) s[j] = fmaf(xv, wc[b * 8 + j], s[j]); // s_load
        }

        float p[NTRI];
        int u = 0;
        #pragma unroll
        for (int i = 0; i < HS; ++i)
            #pragma unroll
            for (int j = i; j < HS; ++j) { p[u] = wave_sum64(wv[i] * s[j]); ++u; }

        if (lane == 63) {
            float4* o = (float4*)&y_out[(size_t)((tile0 + t) * GPB + wave) * 16];
            o[0] = make_float4(p[0],  p[1],  p[2],  p[3]);
            o[1] = make_float4(p[4],  p[5],  p[6],  p[7]);
            o[2] = make_float4(p[8],  p[9],  p[10], p[11]);
            o[3] = make_float4(p[12], p[13], p[14], 0.f);
        }
        __builtin_amdgcn_s_barrier();            // release cur for next staging
    }
}

// ------------------------------------------------------------------ k_eig
// One thread per matrix: 5x5 Jacobi eigensolve -> logm -> tri -> linear.
__global__ __launch_bounds__(64) void k_eig(const float* __restrict__ y_in,
                                            const float* __restrict__ lin_w,
                                            const float* __restrict__ lin_b,
                                            float* __restrict__ out) {
    __shared__ float lws[NCLS * NTRI];
    __shared__ float lbs[NCLS];
    int tid = threadIdx.x;
    for (int i = tid; i < NCLS * NTRI; i += 64) lws[i] = lin_w[i];
    if (tid < NCLS) lbs[tid] = lin_b[tid];
    __syncthreads();

    int m = blockIdx.x * 64 + tid;
    const float4* yin = (const float4*)&y_in[(size_t)m * 16];
    float4 q0 = yin[0], q1 = yin[1], q2 = yin[2], q3 = yin[3];
    float tri[16] = {q0.x, q0.y, q0.z, q0.w, q1.x, q1.y, q1.z, q1.w,
                     q2.x, q2.y, q2.z, q2.w, q3.x, q3.y, q3.z, q3.w};

    float A[HS][HS], V[HS][HS];
    int t = 0;
    #pragma unroll
    for (int i = 0; i < HS; ++i)
        #pragma unroll
        for (int j = i; j < HS; ++j) { A[i][j] = tri[t]; A[j][i] = tri[t]; ++t; }
    #pragma unroll
    for (int i = 0; i < HS; ++i)
        #pragma unroll
        for (int j = 0; j < HS; ++j) V[i][j] = (i == j) ? 1.f : 0.f;

    #pragma unroll
    for (int sweep = 0; sweep < 6; ++sweep) {
        #pragma unroll
        for (int p = 0; p < HS - 1; ++p) {
            #pragma unroll
            for (int q = p + 1; q < HS; ++q) {
                float apq = A[p][q];
                float app = A[p][p], aqq = A[q][q];
                bool nz = fabsf(apq) > 1e-30f;
                float denom = nz ? 2.f * apq : 1.f;
                float tau = (aqq - app) / denom;
                float tt = 1.f / (fabsf(tau) + sqrtf(fmaf(tau, tau, 1.f)));
                tt = copysignf(tt, tau);
                tt = nz ? tt : 0.f;
                float c = rsqrtf(fmaf(tt, tt, 1.f));
                float sn = tt * c;
                #pragma unroll
                for (int k = 0; k < HS; ++k) {
                    float akp = A[k][p], akq = A[k][q];
                    A[k][p] = fmaf(c, akp, -sn * akq);
                    A[k][q] = fmaf(sn, akp,  c * akq);
                }
                #pragma unroll
                for (int k = 0; k < HS; ++k) {
                    float apk = A[p][k], aqk = A[q][k];
                    A[p][k] = fmaf(c, apk, -sn * aqk);
                    A[q][k] = fmaf(sn, apk,  c * aqk);
                }
                #pragma unroll
                for (int k = 0; k < HS; ++k) {
                    float vkp = V[k][p], vkq = V[k][q];
                    V[k][p] = fmaf(c, vkp, -sn * vkq);
                    V[k][q] = fmaf(sn, vkp,  c * vkq);
                }
            }
        }
    }

    float lwv[HS];
    #pragma unroll
    for (int i = 0; i < HS; ++i) lwv[i] = logf(fmaxf(A[i][i], EPSV));

    float tri2[NTRI];
    t = 0;
    #pragma unroll
    for (int i = 0; i < HS; ++i) {
        float vi[HS];
        #pragma unroll
        for (int k = 0; k < HS; ++k) vi[k] = V[i][k] * lwv[k];
        #pragma unroll
        for (int j = i; j < HS; ++j) {
            float acc = 0.f;
            #pragma unroll
            for (int k = 0; k < HS; ++k) acc = fmaf(vi[k], V[j][k], acc);
            tri2[t++] = acc;
        }
    }

    #pragma unroll
    for (int c = 0; c < NCLS; ++c) {
        float acc = lbs[c];
        #pragma unroll
        for (int k = 0; k < NTRI; ++k) acc = fmaf(tri2[k], lws[c * NTRI + k], acc);
        out[(size_t)m * NCLS + c] = acc;
    }
}

// ----------------------------------------------------------------- launch
extern "C" void kernel_launch(void* const* d_in, const int* in_sizes, int n_in,
                              void* d_out, int out_size, void* d_ws, size_t ws_size,
                              hipStream_t stream) {
    const float* x     = (const float*)d_in[0];
    const float* W1    = (const float*)d_in[1];
    const float* W2    = (const float*)d_in[2];
    const float* W3    = (const float*)d_in[3];
    const float* lin_w = (const float*)d_in[4];
    const float* lin_b = (const float*)d_in[5];
    float* out = (float*)d_out;
    float* ws  = (float*)d_ws;
    float* wc  = ws;               // 456 floats, padded [57][8]
    float* y   = ws + 512;         // 16384*16 floats

    k_setup<<<1, 128, 0, stream>>>(W1, W2, W3, wc);
    k_main<<<BATCH / (GPB * NT), 256, 0, stream>>>(x, wc, y);
    k_eig<<<BATCH / 64, 64, 0, stream>>>(y, lin_w, lin_b, out);
}

// Round 5
// 57.775 us; speedup vs baseline: 1.1445x; 1.1445x over previous
//
#include <hip/hip_runtime.h>
#include <math.h>

#define BATCH 16384
#define N0 57
#define NX 3249          // 57*57
#define HS 5
#define NCLS 17
#define NTRI 15
#define EPSV 1e-4f

// ---------------------------------------------------------------- helpers
template<int CTRL>
__device__ __forceinline__ float dpp_mov0(float x) {
    return __int_as_float(__builtin_amdgcn_update_dpp(
        0, __float_as_int(x), CTRL, 0xF, 0xF, true));
}
// full 64-lane sum, result valid in lane 63, pure VALU (no LDS pipe)
__device__ __forceinline__ float wave_sum64(float x) {
    x += dpp_mov0<0x111>(x);   // row_shr:1
    x += dpp_mov0<0x112>(x);   // row_shr:2
    x += dpp_mov0<0x114>(x);   // row_shr:4
    x += dpp_mov0<0x118>(x);   // row_shr:8
    x += dpp_mov0<0x142>(x);   // row_bcast:15
    x += dpp_mov0<0x143>(x);   // row_bcast:31 -> lane 63 = total
    return x;
}

// ---------------------------------------------------------------- k_setup
// wc[57][8] = W1@W2@W3, rows padded to 8
__global__ __launch_bounds__(128) void k_setup(const float* __restrict__ W1,
                                               const float* __restrict__ W2,
                                               const float* __restrict__ W3,
                                               float* __restrict__ wc_out) {
    __shared__ float w23[100];
    int t = threadIdx.x;
    if (t < 100) {
        int k = t / 5, j = t % 5;
        float acc = 0.f;
        for (int l = 0; l < 10; ++l) acc = fmaf(W2[k * 10 + l], W3[l * 5 + j], acc);
        w23[t] = acc;
    }
    __syncthreads();
    if (t < N0) {
        float r[5];
        #pragma unroll
        for (int j = 0; j < 5; ++j) {
            float acc = 0.f;
            for (int k = 0; k < 20; ++k) acc = fmaf(W1[t * 20 + k], w23[k * 5 + j], acc);
            r[j] = acc;
        }
        float4* o = (float4*)&wc_out[t * 8];
        o[0] = make_float4(r[0], r[1], r[2], r[3]);
        o[1] = make_float4(r[4], 0.f, 0.f, 0.f);
    }
}

// ----------------------------------------------------------------- k_main
// No LDS, no barriers. Wave w -> matrix blockIdx*4+w; lane a -> column a.
// Direct coalesced global reads (x[b*57+lane] = 64 consecutive dwords),
// x fully preloaded into registers (static indices), Wc via SGPR s_loads.
__global__ __launch_bounds__(256) void k_main(const float* __restrict__ x,
                                              const float* __restrict__ wc,
                                              float* __restrict__ y_out) {
    const int tid  = threadIdx.x;
    const int lane = tid & 63;
    const int wave = tid >> 6;
    const int m    = blockIdx.x * 4 + wave;

    // per-lane Wc row (left operand of the outer product)
    float wv[HS];
    {
        int a = (lane < N0) ? lane : 0;
        const float4* wp = (const float4*)&wc[a * 8];
        float4 v0 = wp[0];
        float  v4 = wc[a * 8 + 4];
        wv[0] = v0.x; wv[1] = v0.y; wv[2] = v0.z; wv[3] = v0.w; wv[4] = v4;
        if (lane >= N0) { wv[0] = wv[1] = wv[2] = wv[3] = wv[4] = 0.f; }
    }

    // preload entire column strip: 57 coalesced loads, all static indices
    const int lc = (lane < N0) ? lane : 56;          // clamp keeps loads in-bounds
    const float* base = x + (size_t)m * NX + lc;
    float xr[N0];
    #pragma unroll
    for (int b = 0; b < N0; ++b) xr[b] = base[b * N0];

    // s[j](a) = sum_b x[b][a] * wc[b][j]   (wc from scalar cache)
    float s[HS] = {0.f, 0.f, 0.f, 0.f, 0.f};
    #pragma unroll
    for (int b = 0; b < N0; ++b) {
        #pragma unroll
        for (int j = 0; j < HS; ++j) s[j] = fmaf(xr[b], wc[b * 8 + j], s[j]);
    }

    // upper-tri outer product + DPP reduction (VALU only)
    float p[NTRI];
    int u = 0;
    #pragma unroll
    for (int i = 0; i < HS; ++i)
        #pragma unroll
        for (int j = i; j < HS; ++j) { p[u] = wave_sum64(wv[i] * s[j]); ++u; }

    if (lane == 63) {
        float4* o = (float4*)&y_out[(size_t)m * 16];
        o[0] = make_float4(p[0],  p[1],  p[2],  p[3]);
        o[1] = make_float4(p[4],  p[5],  p[6],  p[7]);
        o[2] = make_float4(p[8],  p[9],  p[10], p[11]);
        o[3] = make_float4(p[12], p[13], p[14], 0.f);
    }
}

// ------------------------------------------------------------------ k_eig
// One thread per matrix: 5x5 Jacobi eigensolve -> logm -> tri -> linear.
__global__ __launch_bounds__(64) void k_eig(const float* __restrict__ y_in,
                                            const float* __restrict__ lin_w,
                                            const float* __restrict__ lin_b,
                                            float* __restrict__ out) {
    __shared__ float lws[NCLS * NTRI];
    __shared__ float lbs[NCLS];
    int tid = threadIdx.x;
    for (int i = tid; i < NCLS * NTRI; i += 64) lws[i] = lin_w[i];
    if (tid < NCLS) lbs[tid] = lin_b[tid];
    __syncthreads();

    int m = blockIdx.x * 64 + tid;
    const float4* yin = (const float4*)&y_in[(size_t)m * 16];
    float4 q0 = yin[0], q1 = yin[1], q2 = yin[2], q3 = yin[3];
    float tri[16] = {q0.x, q0.y, q0.z, q0.w, q1.x, q1.y, q1.z, q1.w,
                     q2.x, q2.y, q2.z, q2.w, q3.x, q3.y, q3.z, q3.w};

    float A[HS][HS], V[HS][HS];
    int t = 0;
    #pragma unroll
    for (int i = 0; i < HS; ++i)
        #pragma unroll
        for (int j = i; j < HS; ++j) { A[i][j] = tri[t]; A[j][i] = tri[t]; ++t; }
    #pragma unroll
    for (int i = 0; i < HS; ++i)
        #pragma unroll
        for (int j = 0; j < HS; ++j) V[i][j] = (i == j) ? 1.f : 0.f;

    #pragma unroll
    for (int sweep = 0; sweep < 6; ++sweep) {
        #pragma unroll
        for (int p = 0; p < HS - 1; ++p) {
            #pragma unroll
            for (int q = p + 1; q < HS; ++q) {
                float apq = A[p][q];
                float app = A[p][p], aqq = A[q][q];
                bool nz = fabsf(apq) > 1e-30f;
                float denom = nz ? 2.f * apq : 1.f;
                float tau = (aqq - app) / denom;
                float tt = 1.f / (fabsf(tau) + sqrtf(fmaf(tau, tau, 1.f)));
                tt = copysignf(tt, tau);
                tt = nz ? tt : 0.f;
                float c = rsqrtf(fmaf(tt, tt, 1.f));
                float sn = tt * c;
                #pragma unroll
                for (int k = 0; k < HS; ++k) {
                    float akp = A[k][p], akq = A[k][q];
                    A[k][p] = fmaf(c, akp, -sn * akq);
                    A[k][q] = fmaf(sn, akp,  c * akq);
                }
                #pragma unroll
                for (int k = 0; k < HS; ++k) {
                    float apk = A[p][k], aqk = A[q][k];
                    A[p][k] = fmaf(c, apk, -sn * aqk);
                    A[q][k] = fmaf(sn, apk,  c * aqk);
                }
                #pragma unroll
                for (int k = 0; k < HS; ++k) {
                    float vkp = V[k][p], vkq = V[k][q];
                    V[k][p] = fmaf(c, vkp, -sn * vkq);
                    V[k][q] = fmaf(sn, vkp,  c * vkq);
                }
            }
        }
    }

    float lwv[HS];
    #pragma unroll
    for (int i = 0; i < HS; ++i) lwv[i] = logf(fmaxf(A[i][i], EPSV));

    float tri2[NTRI];
    t = 0;
    #pragma unroll
    for (int i = 0; i < HS; ++i) {
        float vi[HS];
        #pragma unroll
        for (int k = 0; k < HS; ++k) vi[k] = V[i][k] * lwv[k];
        #pragma unroll
        for (int j = i; j < HS; ++j) {
            float acc = 0.f;
            #pragma unroll
            for (int k = 0; k < HS; ++k) acc = fmaf(vi[k], V[j][k], acc);
            tri2[t++] = acc;
        }
    }

    #pragma unroll
    for (int c = 0; c < NCLS; ++c) {
        float acc = lbs[c];
        #pragma unroll
        for (int k = 0; k < NTRI; ++k) acc = fmaf(tri2[k], lws[c * NTRI + k], acc);
        out[(size_t)m * NCLS + c] = acc;
    }
}

// ----------------------------------------------------------------- launch
extern "C" void kernel_launch(void* const* d_in, const int* in_sizes, int n_in,
                              void* d_out, int out_size, void* d_ws, size_t ws_size,
                              hipStream_t stream) {
    const float* x     = (const float*)d_in[0];
    const float* W1    = (const float*)d_in[1];
    const float* W2    = (const float*)d_in[2];
    const float* W3    = (const float*)d_in[3];
    const float* lin_w = (const float*)d_in[4];
    const float* lin_b = (const float*)d_in[5];
    float* out = (float*)d_out;
    float* ws  = (float*)d_ws;
    float* wc  = ws;               // 456 floats, padded [57][8]
    float* y   = ws + 512;         // 16384*16 floats

    k_setup<<<1, 128, 0, stream>>>(W1, W2, W3, wc);
    k_main<<<BATCH / 4, 256, 0, stream>>>(x, wc, y);
    k_eig<<<BATCH / 64, 64, 0, stream>>>(y, lin_w, lin_b, out);
}

// Round 6
// 52.838 us; speedup vs baseline: 1.2515x; 1.0934x over previous
//
#include <hip/hip_runtime.h>
#include <math.h>

#define BATCH 16384
#define N0 57
#define NX 3249          // 57*57
#define HS 5
#define NCLS 17
#define NTRI 15
#define EPSV 1e-4f

// ---------------------------------------------------------------- helpers
template<int CTRL>
__device__ __forceinline__ float dpp_mov0(float x) {
    return __int_as_float(__builtin_amdgcn_update_dpp(
        0, __float_as_int(x), CTRL, 0xF, 0xF, true));
}
// full 64-lane sum, result valid in lane 63, pure VALU (no LDS pipe)
__device__ __forceinline__ float wave_sum64(float x) {
    x += dpp_mov0<0x111>(x);   // row_shr:1
    x += dpp_mov0<0x112>(x);   // row_shr:2
    x += dpp_mov0<0x114>(x);   // row_shr:4
    x += dpp_mov0<0x118>(x);   // row_shr:8
    x += dpp_mov0<0x142>(x);   // row_bcast:15
    x += dpp_mov0<0x143>(x);   // row_bcast:31 -> lane 63 = total
    return x;
}

__device__ __forceinline__ float frcp(float x)  { return __builtin_amdgcn_rcpf(x); }
__device__ __forceinline__ float frsq(float x)  { return __builtin_amdgcn_rsqf(x); }
__device__ __forceinline__ float fsqrt(float x) { return __builtin_amdgcn_sqrtf(x); }

// ---------------------------------------------------------------- k_setup
// wc[57][8] = W1@W2@W3, rows padded to 8
__global__ __launch_bounds__(128) void k_setup(const float* __restrict__ W1,
                                               const float* __restrict__ W2,
                                               const float* __restrict__ W3,
                                               float* __restrict__ wc_out) {
    __shared__ float w23[100];
    int t = threadIdx.x;
    if (t < 100) {
        int k = t / 5, j = t % 5;
        float acc = 0.f;
        for (int l = 0; l < 10; ++l) acc = fmaf(W2[k * 10 + l], W3[l * 5 + j], acc);
        w23[t] = acc;
    }
    __syncthreads();
    if (t < N0) {
        float r[5];
        #pragma unroll
        for (int j = 0; j < 5; ++j) {
            float acc = 0.f;
            for (int k = 0; k < 20; ++k) acc = fmaf(W1[t * 20 + k], w23[k * 5 + j], acc);
            r[j] = acc;
        }
        float4* o = (float4*)&wc_out[t * 8];
        o[0] = make_float4(r[0], r[1], r[2], r[3]);
        o[1] = make_float4(r[4], 0.f, 0.f, 0.f);
    }
}

// ----------------------------------------------------------------- k_main
// UNCHANGED from round 5 (best so far) — isolates this round's k_eig delta.
// No LDS, no barriers. Wave w -> matrix blockIdx*4+w; lane a -> column a.
__global__ __launch_bounds__(256) void k_main(const float* __restrict__ x,
                                              const float* __restrict__ wc,
                                              float* __restrict__ y_out) {
    const int tid  = threadIdx.x;
    const int lane = tid & 63;
    const int wave = tid >> 6;
    const int m    = blockIdx.x * 4 + wave;

    // per-lane Wc row (left operand of the outer product)
    float wv[HS];
    {
        int a = (lane < N0) ? lane : 0;
        const float4* wp = (const float4*)&wc[a * 8];
        float4 v0 = wp[0];
        float  v4 = wc[a * 8 + 4];
        wv[0] = v0.x; wv[1] = v0.y; wv[2] = v0.z; wv[3] = v0.w; wv[4] = v4;
        if (lane >= N0) { wv[0] = wv[1] = wv[2] = wv[3] = wv[4] = 0.f; }
    }

    // preload entire column strip: 57 coalesced loads, all static indices
    const int lc = (lane < N0) ? lane : 56;          // clamp keeps loads in-bounds
    const float* base = x + (size_t)m * NX + lc;
    float xr[N0];
    #pragma unroll
    for (int b = 0; b < N0; ++b) xr[b] = base[b * N0];

    // s[j](a) = sum_b x[b][a] * wc[b][j]   (wc from scalar cache)
    float s[HS] = {0.f, 0.f, 0.f, 0.f, 0.f};
    #pragma unroll
    for (int b = 0; b < N0; ++b) {
        #pragma unroll
        for (int j = 0; j < HS; ++j) s[j] = fmaf(xr[b], wc[b * 8 + j], s[j]);
    }

    // upper-tri outer product + DPP reduction (VALU only)
    float p[NTRI];
    int u = 0;
    #pragma unroll
    for (int i = 0; i < HS; ++i)
        #pragma unroll
        for (int j = i; j < HS; ++j) { p[u] = wave_sum64(wv[i] * s[j]); ++u; }

    if (lane == 63) {
        float4* o = (float4*)&y_out[(size_t)m * 16];
        o[0] = make_float4(p[0],  p[1],  p[2],  p[3]);
        o[1] = make_float4(p[4],  p[5],  p[6],  p[7]);
        o[2] = make_float4(p[8],  p[9],  p[10], p[11]);
        o[3] = make_float4(p[12], p[13], p[14], 0.f);
    }
}

// ------------------------------------------------------------------ k_eig
// One thread per matrix. Fast-math natives (rcp/rsq/sqrt/log2) cut the
// serial rotation chain ~3x; lin_w/lin_b via s_load (no LDS, no barrier).
__global__ __launch_bounds__(64) void k_eig(const float* __restrict__ y_in,
                                            const float* __restrict__ lin_w,
                                            const float* __restrict__ lin_b,
                                            float* __restrict__ out) {
    int m = blockIdx.x * 64 + threadIdx.x;
    const float4* yin = (const float4*)&y_in[(size_t)m * 16];
    float4 q0 = yin[0], q1 = yin[1], q2 = yin[2], q3 = yin[3];
    float tri[16] = {q0.x, q0.y, q0.z, q0.w, q1.x, q1.y, q1.z, q1.w,
                     q2.x, q2.y, q2.z, q2.w, q3.x, q3.y, q3.z, q3.w};

    float A[HS][HS], V[HS][HS];
    int t = 0;
    #pragma unroll
    for (int i = 0; i < HS; ++i)
        #pragma unroll
        for (int j = i; j < HS; ++j) { A[i][j] = tri[t]; A[j][i] = tri[t]; ++t; }
    #pragma unroll
    for (int i = 0; i < HS; ++i)
        #pragma unroll
        for (int j = 0; j < HS; ++j) V[i][j] = (i == j) ? 1.f : 0.f;

    #pragma unroll
    for (int sweep = 0; sweep < 6; ++sweep) {
        #pragma unroll
        for (int p = 0; p < HS - 1; ++p) {
            #pragma unroll
            for (int q = p + 1; q < HS; ++q) {
                float apq = A[p][q];
                float app = A[p][p], aqq = A[q][q];
                bool nz = fabsf(apq) > 1e-30f;
                // theta = (aqq-app)/(2*apq) via native rcp
                float theta = (aqq - app) * 0.5f * frcp(apq);
                float tt = frcp(fabsf(theta) + fsqrt(fmaf(theta, theta, 1.f)));
                tt = copysignf(tt, theta);
                tt = nz ? tt : 0.f;
                float c = frsq(fmaf(tt, tt, 1.f));
                float sn = tt * c;
                #pragma unroll
                for (int k = 0; k < HS; ++k) {
                    float akp = A[k][p], akq = A[k][q];
                    A[k][p] = fmaf(c, akp, -sn * akq);
                    A[k][q] = fmaf(sn, akp,  c * akq);
                }
                #pragma unroll
                for (int k = 0; k < HS; ++k) {
                    float apk = A[p][k], aqk = A[q][k];
                    A[p][k] = fmaf(c, apk, -sn * aqk);
                    A[q][k] = fmaf(sn, apk,  c * aqk);
                }
                #pragma unroll
                for (int k = 0; k < HS; ++k) {
                    float vkp = V[k][p], vkq = V[k][q];
                    V[k][p] = fmaf(c, vkp, -sn * vkq);
                    V[k][q] = fmaf(sn, vkp,  c * vkq);
                }
            }
        }
    }

    float lwv[HS];
    #pragma unroll
    for (int i = 0; i < HS; ++i)
        lwv[i] = 0.69314718056f * __log2f(fmaxf(A[i][i], EPSV));

    float tri2[NTRI];
    t = 0;
    #pragma unroll
    for (int i = 0; i < HS; ++i) {
        float vi[HS];
        #pragma unroll
        for (int k = 0; k < HS; ++k) vi[k] = V[i][k] * lwv[k];
        #pragma unroll
        for (int j = i; j < HS; ++j) {
            float acc = 0.f;
            #pragma unroll
            for (int k = 0; k < HS; ++k) acc = fmaf(vi[k], V[j][k], acc);
            tri2[t++] = acc;
        }
    }

    // linear 15 -> 17; lin_w/lin_b uniform indices -> scalar loads
    #pragma unroll
    for (int c = 0; c < NCLS; ++c) {
        float acc = lin_b[c];
        #pragma unroll
        for (int k = 0; k < NTRI; ++k) acc = fmaf(tri2[k], lin_w[c * NTRI + k], acc);
        out[(size_t)m * NCLS + c] = acc;
    }
}

// ----------------------------------------------------------------- launch
extern "C" void kernel_launch(void* const* d_in, const int* in_sizes, int n_in,
                              void* d_out, int out_size, void* d_ws, size_t ws_size,
                              hipStream_t stream) {
    const float* x     = (const float*)d_in[0];
    const float* W1    = (const float*)d_in[1];
    const float* W2    = (const float*)d_in[2];
    const float* W3    = (const float*)d_in[3];
    const float* lin_w = (const float*)d_in[4];
    const float* lin_b = (const float*)d_in[5];
    float* out = (float*)d_out;
    float* ws  = (float*)d_ws;
    float* wc  = ws;               // 456 floats, padded [57][8]
    float* y   = ws + 512;         // 16384*16 floats

    k_setup<<<1, 128, 0, stream>>>(W1, W2, W3, wc);
    k_main<<<BATCH / 4, 256, 0, stream>>>(x, wc, y);
    k_eig<<<BATCH / 64, 64, 0, stream>>>(y, lin_w, lin_b, out);
}